// Round 4
// baseline (251.920 us; speedup 1.0000x reference)
//
#include <hip/hip_runtime.h>

typedef __attribute__((ext_vector_type(8))) short bf16x8;
typedef __attribute__((ext_vector_type(4))) float f32x4;

constexpr int BROWS = 131072;
constexpr int DDIM  = 128;
constexpr int NTILES = BROWS / 16;        // 8192 row-tiles
constexpr int CLSBLOCKS = 2048;           // blocks per output-class
constexpr int ITERS = NTILES / CLSBLOCKS; // 4

__device__ __forceinline__ short to_bf16(float f) {
    unsigned u = __builtin_bit_cast(unsigned, f);
    u = (u + 0x7FFFu + ((u >> 16) & 1u)) >> 16;   // RTNE
    return (short)u;
}

__device__ __forceinline__ bf16x8 cvt8(f32x4 lo, f32x4 hi) {
    bf16x8 r;
#pragma unroll
    for (int i = 0; i < 4; ++i) { r[i] = to_bf16(lo[i]); r[i + 4] = to_bf16(hi[i]); }
    return r;
}

// Operand-swapped MFMA GEMM: D = W_tile * A_tile.
//  A-operand (wfrag): lane m = l16 (output col), k = ks*32 + lq*8 + j
//  B-operand (afrag): lane n = l16 (b-row),      k = ks*32 + lq*8 + j
//  D: col(l16) = b-row, row(lq*4+r) = output col -> lane stores f32x4 of 4
//  consecutive output columns at one b-row: global_store_dwordx4 epilogue.
__global__ void __launch_bounds__(256, 4)
lfm_kernel(const float* __restrict__ state, const float* __restrict__ W,
           const float* __restrict__ bias, float* __restrict__ out) {
    const int lane = threadIdx.x & 63;
    const int wave = threadIdx.x >> 6;
    const int l16  = lane & 15;
    const int lq   = lane >> 4;

    const int cls = blockIdx.x & 1;      // 0 -> delta (o=0), 1 -> var (o=1)
    const int tb  = blockIdx.x >> 1;     // 0..2047
    const int colbase = wave * 32;       // this wave's 32 cols within the plane

    // ---- W fragments + bias (once per block; W/bias are L2/L3-hot) ----
    bf16x8 wfrag[2][4];
    f32x4  bias4[2];
#pragma unroll
    for (int ct = 0; ct < 2; ++ct) {
        const int n = colbase + ct * 16 + l16;
        const float* wrow = W + n * 256 + cls * 128;   // W[n][cls][*]
#pragma unroll
        for (int ks = 0; ks < 4; ++ks) {
            f32x4 lo = *reinterpret_cast<const f32x4*>(wrow + ks * 32 + lq * 8);
            f32x4 hi = *reinterpret_cast<const f32x4*>(wrow + ks * 32 + lq * 8 + 4);
            wfrag[ct][ks] = cvt8(lo, hi);
        }
        const int c0 = colbase + ct * 16 + lq * 4;
#pragma unroll
        for (int r = 0; r < 4; ++r)
            bias4[ct][r] = bias[(c0 + r) * 2 + cls];
    }

    float* oplane = out + (size_t)cls * BROWS * 128;

#define LOADT(BUF, T) { \
    const float* srow = state + ((size_t)((T) * 16 + l16)) * DDIM + lq * 8; \
    _Pragma("unroll") \
    for (int ks = 0; ks < 4; ++ks) { \
        BUF[2 * ks]     = *reinterpret_cast<const f32x4*>(srow + ks * 32); \
        BUF[2 * ks + 1] = *reinterpret_cast<const f32x4*>(srow + ks * 32 + 4); \
    } }

#define COMPUTE(BUF, T) { \
    f32x4 acc0 = bias4[0], acc1 = bias4[1]; \
    _Pragma("unroll") \
    for (int ks = 0; ks < 4; ++ks) { \
        bf16x8 af = cvt8(BUF[2 * ks], BUF[2 * ks + 1]); \
        acc0 = __builtin_amdgcn_mfma_f32_16x16x32_bf16(wfrag[0][ks], af, acc0, 0, 0, 0); \
        acc1 = __builtin_amdgcn_mfma_f32_16x16x32_bf16(wfrag[1][ks], af, acc1, 0, 0, 0); \
    } \
    float* orow = oplane + ((size_t)((T) * 16 + l16)) * 128; \
    *reinterpret_cast<f32x4*>(orow + colbase + lq * 4)      = acc0; \
    *reinterpret_cast<f32x4*>(orow + colbase + 16 + lq * 4) = acc1; }

    // depth-2 prefetch pipeline over the 4 row-tiles this block owns
    f32x4 rawA[8], rawB[8];
    LOADT(rawA, tb)
    LOADT(rawB, (tb + CLSBLOCKS))
    COMPUTE(rawA, tb)
    LOADT(rawA, (tb + 2 * CLSBLOCKS))
    COMPUTE(rawB, (tb + CLSBLOCKS))
    LOADT(rawB, (tb + 3 * CLSBLOCKS))
    COMPUTE(rawA, (tb + 2 * CLSBLOCKS))
    COMPUTE(rawB, (tb + 3 * CLSBLOCKS))
#undef LOADT
#undef COMPUTE
}

extern "C" void kernel_launch(void* const* d_in, const int* in_sizes, int n_in,
                              void* d_out, int out_size, void* d_ws, size_t ws_size,
                              hipStream_t stream) {
    const float* state = (const float*)d_in[0];
    const float* W     = (const float*)d_in[1];
    const float* bias  = (const float*)d_in[2];
    float* out = (float*)d_out;
    hipLaunchKernelGGL(lfm_kernel, dim3(2 * CLSBLOCKS), dim3(256), 0, stream,
                       state, W, bias, out);
}